// Round 4
// baseline (310.870 us; speedup 1.0000x reference)
//
#include <hip/hip_runtime.h>
#include <stdint.h>
#include <stddef.h>

// Problem geometry (B=4, S=2048, DIN=4096, DOUT=4096)
constexpr int MDIM = 8192;   // B*S
constexpr int NDIM = 4096;   // DOUT
constexpr int KDIM = 4096;   // DIN

using f32x4  = __attribute__((ext_vector_type(4)))  float;
using f32x16 = __attribute__((ext_vector_type(16))) float;
using s16x4  = __attribute__((ext_vector_type(4)))  short;
using s16x8  = __attribute__((ext_vector_type(8)))  short;
using i32x4  = __attribute__((ext_vector_type(4)))  int;

__device__ __forceinline__ short f32_to_bf16_rn(float f) {
  union { float f; uint32_t u; } v; v.f = f;
  uint32_t r = (v.u + 0x7FFFu + ((v.u >> 16) & 1u)) >> 16;  // RTN-even
  return (short)(uint16_t)r;
}

// ---------------- prepass: f32 -> bf16 ----------------
__global__ void __launch_bounds__(256) cvt_x_kernel(const float* __restrict__ in,
                                                    short* __restrict__ out, int n8) {
  int i = blockIdx.x * 256 + threadIdx.x;
  const int stride = gridDim.x * 256;
  for (; i < n8; i += stride) {
    const f32x4* p = (const f32x4*)(in + (size_t)i * 8);
    f32x4 a = p[0];
    f32x4 b = p[1];
    s16x8 o;
#pragma unroll
    for (int j = 0; j < 4; ++j) { o[j] = f32_to_bf16_rn(a[j]); o[j + 4] = f32_to_bf16_rn(b[j]); }
    *(s16x8*)(out + (size_t)i * 8) = o;
  }
}

// ---------------- prepass: int32 (quantized weight) -> bf16 (exact) ----------------
__global__ void __launch_bounds__(256) cvt_w_kernel(const int* __restrict__ in,
                                                    short* __restrict__ out, int n8) {
  int i = blockIdx.x * 256 + threadIdx.x;
  const int stride = gridDim.x * 256;
  for (; i < n8; i += stride) {
    const i32x4* p = (const i32x4*)(in + (size_t)i * 8);
    i32x4 a = p[0];
    i32x4 b = p[1];
    s16x8 o;
#pragma unroll
    for (int j = 0; j < 4; ++j) {
      o[j]     = f32_to_bf16_rn((float)a[j]);
      o[j + 4] = f32_to_bf16_rn((float)b[j]);
    }
    *(s16x8*)(out + (size_t)i * 8) = o;
  }
}

// =====================================================================
// 256x256 8-phase GEMM (m201 template) with 32x32x16 MFMA:
//   A [M][K] bf16, Bw [N][K] bf16 (= B^T), C = A*Bw^T * scale + bias
// LDS per matrix per buffer (32 KiB): row-major [256 rows][64 B] per
// ks-half, XOR swizzle phys = lin ^ (((lin>>9)&1)<<5)  (st_16x32).
// Staged via global_load_lds (linear dest) from inverse-swizzled source.
// Half-tile stream order per K-tile: [B-ks0, A-ks0, B-ks1, A-ks1].
// Wave tile 128x64 = 4x2 frags of 32x32; K-tile 64 = 2 ks-halves x 2 ksteps.
// =====================================================================

#define BAR asm volatile("s_barrier" ::: "memory")
#define WAITVM6 asm volatile("s_waitcnt vmcnt(6)" ::: "memory")
#define WAITVM0 asm volatile("s_waitcnt vmcnt(0)" ::: "memory")

#define GLL(src, dst) __builtin_amdgcn_global_load_lds(                     \
    (const __attribute__((address_space(1))) void*)(src),                   \
    (__attribute__((address_space(3))) void*)(dst), 16, 0, 0)

// grow: const char* global row base (matrix + tile_row0*KDIM), row stride 8192 B
// ldsmat: 0 (A) or 65536 (B)
#define STAGE(grow, ldsmat, ks, tau) do {                                   \
  const int buf_ = (tau) & 1;                                               \
  GLL((grow) + (size_t)r0 * 8192 + (size_t)(tau) * 128 + (ks) * 64 + cb,    \
      lds + (ldsmat) + buf_ * 32768 + (ks) * 16384 + t * 16);               \
  GLL((grow) + (size_t)r1 * 8192 + (size_t)(tau) * 128 + (ks) * 64 + cb,    \
      lds + (ldsmat) + buf_ * 32768 + (ks) * 16384 + 8192 + t * 16);        \
} while (0)

// 32x32x16 operand reads: lane holds row/col = lane&31, k = (lane>>5)*8 + e.
// loff0/loff1 precomputed per-lane (ksel 0/1), swizzle XOR-composed.
#define LDA32(cur, ks, fi, ksel) (*(const s16x8*)(lds + (cur) * 32768       \
    + (ks) * 16384 + wm * 8192 + (fi) * 2048 + ((ksel) ? loff1 : loff0)))
#define LDB32(cur, ks, fj, ksel) (*(const s16x8*)(lds + 65536               \
    + (cur) * 32768 + (ks) * 16384 + wn * 4096 + (fj) * 2048                \
    + ((ksel) ? loff1 : loff0)))

#define READ_B32(cur, ks) do {                                              \
  bf[0][0] = LDB32(cur, ks, 0, 0); bf[0][1] = LDB32(cur, ks, 0, 1);         \
  bf[1][0] = LDB32(cur, ks, 1, 0); bf[1][1] = LDB32(cur, ks, 1, 1);         \
} while (0)
#define READ_A32(cur, ks, fbase) do {                                       \
  af[0][0] = LDA32(cur, ks, (fbase), 0);                                    \
  af[0][1] = LDA32(cur, ks, (fbase), 1);                                    \
  af[1][0] = LDA32(cur, ks, (fbase) + 1, 0);                                \
  af[1][1] = LDA32(cur, ks, (fbase) + 1, 1);                                \
} while (0)

#define MFMA8(fbase) do {                                                   \
  __builtin_amdgcn_s_setprio(1);                                            \
  _Pragma("unroll") for (int ks_ = 0; ks_ < 2; ++ks_)                       \
  _Pragma("unroll") for (int fi_ = 0; fi_ < 2; ++fi_)                       \
  _Pragma("unroll") for (int fj_ = 0; fj_ < 2; ++fj_)                       \
    acc[(fbase) + fi_][fj_] = __builtin_amdgcn_mfma_f32_32x32x16_bf16(      \
        af[fi_][ks_], bf[fj_][ks_], acc[(fbase) + fi_][fj_], 0, 0, 0);      \
  __builtin_amdgcn_s_setprio(0);                                            \
} while (0)

// One K-tile = 4 phases. nstage: 4=full stream, 1=only ph1 stage, 0=none.
// endvm: 6 -> vmcnt(6), 0 -> vmcnt(0), -1 -> none.
#define KTILE(t_, cur, nstage, endvm) do {                                  \
  /* ph1: ks0, acc rows 0-1 */                                              \
  READ_B32(cur, 0); READ_A32(cur, 0, 0);                                    \
  if ((nstage) >= 1) STAGE(Arow, 0, 1, (t_) + 1);        /* t+1 q3: A-ks1 */\
  BAR; MFMA8(0); BAR;                                                       \
  /* ph2: ks0, acc rows 2-3 (reuse bf) */                                   \
  READ_A32(cur, 0, 2);                                                      \
  if ((nstage) == 4) STAGE(Brow, 65536, 0, (t_) + 2);    /* t+2 q0: B-ks0 */\
  BAR; MFMA8(2); BAR;                                                       \
  /* ph3: ks1, acc rows 0-1 */                                              \
  READ_B32(cur, 1); READ_A32(cur, 1, 0);                                    \
  if ((nstage) == 4) STAGE(Arow, 0, 0, (t_) + 2);        /* t+2 q1: A-ks0 */\
  BAR; MFMA8(0); BAR;                                                       \
  /* ph4: ks1, acc rows 2-3 */                                              \
  READ_A32(cur, 1, 2);                                                      \
  if ((nstage) == 4) STAGE(Brow, 65536, 1, (t_) + 2);    /* t+2 q2: B-ks1 */\
  BAR; MFMA8(2);                                                            \
  if ((endvm) == 6) { WAITVM6; } else if ((endvm) == 0) { WAITVM0; }        \
  BAR;                                                                      \
} while (0)

__global__ void __launch_bounds__(512, 2) gemm_bf16_8phase(
    const short* __restrict__ A, const short* __restrict__ Bw,
    const float* __restrict__ scale_p, const float* __restrict__ bias,
    float* __restrict__ out) {
  __shared__ __align__(16) char lds[131072];

  const int t      = threadIdx.x;        // 0..511
  const int lane   = t & 63;
  const int wave   = t >> 6;
  const int wm     = wave >> 2;          // 0..1  (row half: 128 rows)
  const int wn     = wave & 3;           // 0..3  (col quarter: 64 cols)
  const int l31    = lane & 31;

  // 32x32 operand read offsets within a ks-half region ([256 rows][64B]):
  //   row-in-region = frag_base + (lane&31); byte-in-row = ksel*32 + (lane>>5)*16
  //   phys = row*64 + (bytecol ^ ((row&8)<<2)); row&8 == lane&8.
  // NOTE: ksel*32 and the swizzle both live in byte-bit-5 -> must XOR-compose
  // (round-2 lesson: '+' would carry into bit 6).
  const int rowpart = (lane & 15) * 64 + ((lane >> 4) & 1) * 1024;
  const int swz     = (lane & 8) << 2;
  const int hi16    = (lane >> 5) * 16;
  const int loff0   = rowpart + (hi16 ^ swz);
  const int loff1   = rowpart + ((32 + hi16) ^ swz);

  // stage decode: LDS slot o = l*8192 + t*16 (+ks*16384) holds element at
  // a = o ^ (((o>>9)&1)<<5); here bit9 of o depends only on t.
  const int ax = ((t >> 5) & 1) << 5;
  const int a0 = (t * 16) ^ ax;
  const int a1 = (8192 + t * 16) ^ ax;
  const int r0 = (((a0 >> 10) & 15) << 4) | ((a0 >> 6) & 15);
  const int r1 = (((a1 >> 10) & 15) << 4) | ((a1 >> 6) & 15);
  const int cb = a0 & 63;                // col byte within 64B row (same for l=0,1)

  // XCD-aware swizzle: nwg = 512 (divisible by 8)
  const int bid   = blockIdx.x;
  const int wg    = (bid & 7) * 64 + (bid >> 3);
  const int ntile = wg & 15;             // 16 n-tiles
  const int mtile = wg >> 4;             // 32 m-tiles
  const int m0 = mtile * 256;
  const int n0 = ntile * 256;

  const char* Arow = (const char*)(A + (size_t)m0 * KDIM);
  const char* Brow = (const char*)(Bw + (size_t)n0 * KDIM);

  f32x16 acc[4][2] = {};
  s16x8 af[2][2], bf[2][2];

  // Prologue: tile0 (q0..q3) -> buf0, tile1 (q0..q2) -> buf1; 14 loads/wave.
  STAGE(Brow, 65536, 0, 0);
  STAGE(Arow, 0,     0, 0);
  STAGE(Brow, 65536, 1, 0);
  STAGE(Arow, 0,     1, 0);
  STAGE(Brow, 65536, 0, 1);
  STAGE(Arow, 0,     0, 1);
  STAGE(Brow, 65536, 1, 1);
  WAITVM6;   // tile0 fully landed; 3 half-tiles of tile1 in flight
  BAR;

  // Main: 64 K-tiles total; pairs keep buf index compile-time.
#pragma unroll 1
  for (int tp = 0; tp < 31; ++tp) {
    const int t2 = tp * 2;
    KTILE(t2,     0, 4, 6);
    KTILE(t2 + 1, 1, 4, 6);
  }
  KTILE(62, 0, 1, 0);    // issues last half (tile63 q3), then drain
  KTILE(63, 1, 0, -1);

  // Epilogue: 32x32 D layout col=lane&31, row=(reg&3)+8*(reg>>2)+4*(lane>>5)
  // (m74/m101-verified)
  const float s = scale_p[0];
#pragma unroll
  for (int fj = 0; fj < 2; ++fj) {
    const int col = n0 + wn * 64 + fj * 32 + l31;
    const float bv = bias[col];
#pragma unroll
    for (int fi = 0; fi < 4; ++fi) {
      const int rowbase = m0 + wm * 128 + fi * 32 + ((lane >> 5) << 2);
#pragma unroll
      for (int reg = 0; reg < 16; ++reg) {
        const int row = rowbase + (reg & 3) + ((reg >> 2) << 3);
        out[(size_t)row * NDIM + col] = acc[fi][fj][reg] * s + bv;
      }
    }
  }
}

// ---------------- fallback: m97-style reg-staging with on-the-fly conversion ----------------
constexpr int FTILE = 128;
constexpr int FBK   = 64;

__global__ void __launch_bounds__(256) gemm_raw(
    const float* __restrict__ X, const int* __restrict__ W,
    const float* __restrict__ scale_p, const float* __restrict__ bias,
    float* __restrict__ out) {
  __shared__ short As[FTILE * FBK];
  __shared__ short Bs[FTILE * FBK];

  const int t      = threadIdx.x;
  const int lane   = t & 63;
  const int wave   = t >> 6;
  const int wm     = wave >> 1;
  const int wn     = wave & 1;
  const int lane15   = lane & 15;
  const int laneHalf = lane >> 4;

  const int bid   = blockIdx.x;
  const int wg    = (bid & 7) * 256 + (bid >> 3);
  const int ntile = wg & 31;
  const int mtile = wg >> 5;
  const int m0 = mtile * FTILE;
  const int n0 = ntile * FTILE;

  f32x4 acc[4][4] = {};

  for (int k0 = 0; k0 < KDIM; k0 += FBK) {
    __syncthreads();
#pragma unroll
    for (int r = 0; r < 8; ++r) {
      const int f   = r * 256 + t;
      const int row = f >> 4;
      const int c4  = (f & 15) * 4;
      f32x4 v = *(const f32x4*)(X + (size_t)(m0 + row) * KDIM + (k0 + c4));
      s16x4 h;
#pragma unroll
      for (int j = 0; j < 4; ++j) h[j] = f32_to_bf16_rn(v[j]);
      *(s16x4*)&As[row * FBK + c4] = h;

      i32x4 wv = *(const i32x4*)(W + (size_t)(n0 + row) * KDIM + (k0 + c4));
      s16x4 hw;
#pragma unroll
      for (int j = 0; j < 4; ++j) hw[j] = f32_to_bf16_rn((float)wv[j]);
      *(s16x4*)&Bs[row * FBK + c4] = hw;
    }
    __syncthreads();

#pragma unroll
    for (int kk = 0; kk < FBK; kk += 32) {
      const int kb = kk + laneHalf * 8;
      s16x8 af[4], bf[4];
#pragma unroll
      for (int i = 0; i < 4; ++i) {
        af[i] = *(const s16x8*)&As[(wm * 64 + i * 16 + lane15) * FBK + kb];
        bf[i] = *(const s16x8*)&Bs[(wn * 64 + i * 16 + lane15) * FBK + kb];
      }
#pragma unroll
      for (int i = 0; i < 4; ++i)
#pragma unroll
        for (int j = 0; j < 4; ++j)
          acc[i][j] = __builtin_amdgcn_mfma_f32_16x16x32_bf16(af[i], bf[j], acc[i][j], 0, 0, 0);
    }
  }

  const float s = scale_p[0];
#pragma unroll
  for (int j = 0; j < 4; ++j) {
    const int col = n0 + wn * 64 + j * 16 + lane15;
    const float bv = bias[col];
#pragma unroll
    for (int i = 0; i < 4; ++i) {
      const int row = m0 + wm * 64 + i * 16 + laneHalf * 4;
#pragma unroll
      for (int q = 0; q < 4; ++q)
        out[(size_t)(row + q) * NDIM + col] = acc[i][j][q] * s + bv;
    }
  }
}

extern "C" void kernel_launch(void* const* d_in, const int* in_sizes, int n_in,
                              void* d_out, int out_size, void* d_ws, size_t ws_size,
                              hipStream_t stream) {
  const float* x     = (const float*)d_in[0];
  const int*   w     = (const int*)d_in[1];    // integer inputs materialize as int32
  const float* scale = (const float*)d_in[2];
  const float* bias  = (const float*)d_in[3];
  float* out = (float*)d_out;

  const size_t a_elems = (size_t)MDIM * KDIM;  // 33,554,432
  const size_t b_elems = (size_t)NDIM * KDIM;  // 16,777,216
  const size_t need    = (a_elems + b_elems) * sizeof(short);  // 100,663,296 B

  if (ws_size >= need) {
    short* Abf = (short*)d_ws;
    short* Wbf = Abf + a_elems;
    cvt_x_kernel<<<2048, 256, 0, stream>>>(x, Abf, (int)(a_elems / 8));
    cvt_w_kernel<<<2048, 256, 0, stream>>>(w, Wbf, (int)(b_elems / 8));
    const int nwg = (MDIM / 256) * (NDIM / 256);  // 32*16 = 512
    gemm_bf16_8phase<<<nwg, 512, 0, stream>>>(Abf, Wbf, scale, bias, out);
  } else {
    const int nwg = (MDIM / FTILE) * (NDIM / FTILE);  // 2048
    gemm_raw<<<nwg, 256, 0, stream>>>(x, w, scale, bias, out);
  }
}

// Round 5
// 299.734 us; speedup vs baseline: 1.0372x; 1.0372x over previous
//
#include <hip/hip_runtime.h>
#include <stdint.h>
#include <stddef.h>

// Problem geometry (B=4, S=2048, DIN=4096, DOUT=4096)
constexpr int MDIM = 8192;   // B*S
constexpr int NDIM = 4096;   // DOUT
constexpr int KDIM = 4096;   // DIN

using f32x4 = __attribute__((ext_vector_type(4))) float;
using s16x4 = __attribute__((ext_vector_type(4))) short;
using s16x8 = __attribute__((ext_vector_type(8))) short;
using i32x4 = __attribute__((ext_vector_type(4))) int;

__device__ __forceinline__ short f32_to_bf16_rn(float f) {
  union { float f; uint32_t u; } v; v.f = f;
  uint32_t r = (v.u + 0x7FFFu + ((v.u >> 16) & 1u)) >> 16;  // RTN-even
  return (short)(uint16_t)r;
}

// ---------------- prepass: f32 -> bf16 ----------------
__global__ void __launch_bounds__(256) cvt_x_kernel(const float* __restrict__ in,
                                                    short* __restrict__ out, int n8) {
  int i = blockIdx.x * 256 + threadIdx.x;
  const int stride = gridDim.x * 256;
  for (; i < n8; i += stride) {
    const f32x4* p = (const f32x4*)(in + (size_t)i * 8);
    f32x4 a = p[0];
    f32x4 b = p[1];
    s16x8 o;
#pragma unroll
    for (int j = 0; j < 4; ++j) { o[j] = f32_to_bf16_rn(a[j]); o[j + 4] = f32_to_bf16_rn(b[j]); }
    *(s16x8*)(out + (size_t)i * 8) = o;
  }
}

// ---------------- prepass: int32 (quantized weight) -> bf16 (exact) ----------------
__global__ void __launch_bounds__(256) cvt_w_kernel(const int* __restrict__ in,
                                                    short* __restrict__ out, int n8) {
  int i = blockIdx.x * 256 + threadIdx.x;
  const int stride = gridDim.x * 256;
  for (; i < n8; i += stride) {
    const i32x4* p = (const i32x4*)(in + (size_t)i * 8);
    i32x4 a = p[0];
    i32x4 b = p[1];
    s16x8 o;
#pragma unroll
    for (int j = 0; j < 4; ++j) {
      o[j]     = f32_to_bf16_rn((float)a[j]);
      o[j + 4] = f32_to_bf16_rn((float)b[j]);
    }
    *(s16x8*)(out + (size_t)i * 8) = o;
  }
}

// =====================================================================
// 256x256 GEMM, merged 2-phase-per-K-tile variant of the m201 template,
// 16x16x32 MFMA (round-3 zero-conflict read pattern preserved):
//   A [M][K] bf16, Bw [N][K] bf16 (= B^T), C = A*Bw^T * scale + bias
// LDS per matrix per buffer (32 KiB): subtiled [ks][st_r][16][64B],
// XOR swizzle phys = lin ^ (((lin>>9)&1)<<5)  (st_16x32).
// Staged via global_load_lds (linear dest) from inverse-swizzled source.
// Per K-tile: ph-A {read ks0 (12 b128), stage q2,q3(t+1), BAR, 32 MFMA, BAR}
//             ph-B {read ks1 (12 b128), stage q0,q1(t+2), BAR, 32 MFMA,
//                   vmcnt(4), BAR}
// WAR: q2,q3(t+1) last read in ph-B(t-1) -> >=1 barrier before ph-A(t) stage;
//      q0,q1(t+2) last read in ph-A(t)  -> >=1 barrier before ph-B(t) stage.
// RAW: end-of-t vmcnt(4) leaves only ph-B(t)'s 4 loads in flight -> all of
//      tile t+1 (q0,q1 from ph-B(t-1), q2,q3 from ph-A(t)) landed.
// =====================================================================

#define BAR asm volatile("s_barrier" ::: "memory")
#define WAITVM4 asm volatile("s_waitcnt vmcnt(4)" ::: "memory")
#define WAITVM0 asm volatile("s_waitcnt vmcnt(0)" ::: "memory")

#define GLL(src, dst) __builtin_amdgcn_global_load_lds(                     \
    (const __attribute__((address_space(1))) void*)(src),                   \
    (__attribute__((address_space(3))) void*)(dst), 16, 0, 0)

// grow: const char* global row base (matrix + tile_row0*KDIM), row stride 8192 B
// ldsmat: 0 (A) or 65536 (B)
#define STAGE(grow, ldsmat, ks, tau) do {                                   \
  const int buf_ = (tau) & 1;                                               \
  GLL((grow) + (size_t)r0 * 8192 + (size_t)(tau) * 128 + (ks) * 64 + cb,    \
      lds + (ldsmat) + buf_ * 32768 + (ks) * 16384 + t * 16);               \
  GLL((grow) + (size_t)r1 * 8192 + (size_t)(tau) * 128 + (ks) * 64 + cb,    \
      lds + (ldsmat) + buf_ * 32768 + (ks) * 16384 + 8192 + t * 16);        \
} while (0)

#define LDA(cur, ks, i) (*(const s16x8*)(lds + (cur) * 32768 + (ks) * 16384 \
    + (wm * 8 + (i)) * 1024 + laneoff))
#define LDB(cur, ks, j) (*(const s16x8*)(lds + 65536 + (cur) * 32768        \
    + (ks) * 16384 + (wn * 4 + (j)) * 1024 + laneoff))

#define READ_B4(cur, ks) do {                                               \
  _Pragma("unroll") for (int j = 0; j < 4; ++j) bf[j] = LDB(cur, ks, j);    \
} while (0)
#define READ_A8(cur, ks) do {                                               \
  _Pragma("unroll") for (int i = 0; i < 8; ++i) af[i] = LDA(cur, ks, i);    \
} while (0)

#define MFMA32 do {                                                         \
  __builtin_amdgcn_s_setprio(1);                                            \
  _Pragma("unroll") for (int i = 0; i < 8; ++i)                             \
  _Pragma("unroll") for (int j = 0; j < 4; ++j)                             \
    acc[i][j] = __builtin_amdgcn_mfma_f32_16x16x32_bf16(                    \
        af[i], bf[j], acc[i][j], 0, 0, 0);                                  \
  __builtin_amdgcn_s_setprio(0);                                            \
} while (0)

// One K-tile = 2 phases. nstage: 2=both stages, 1=ph-A stage only, 0=none.
// endvm: 4 -> vmcnt(4), 0 -> vmcnt(0), -1 -> none.
#define KTILE2(t_, cur, nstage, endvm) do {                                 \
  /* ph-A: ks0, all 32 MFMA */                                              \
  READ_B4(cur, 0); READ_A8(cur, 0);                                         \
  if ((nstage) >= 1) {                                                      \
    STAGE(Brow, 65536, 1, (t_) + 1);   /* t+1 q2: B-ks1 */                  \
    STAGE(Arow, 0,     1, (t_) + 1);   /* t+1 q3: A-ks1 */                  \
  }                                                                         \
  BAR; MFMA32; BAR;                                                         \
  /* ph-B: ks1 */                                                           \
  READ_B4(cur, 1); READ_A8(cur, 1);                                         \
  if ((nstage) == 2) {                                                      \
    STAGE(Brow, 65536, 0, (t_) + 2);   /* t+2 q0: B-ks0 */                  \
    STAGE(Arow, 0,     0, (t_) + 2);   /* t+2 q1: A-ks0 */                  \
  }                                                                         \
  BAR; MFMA32;                                                              \
  if ((endvm) == 4) { WAITVM4; } else if ((endvm) == 0) { WAITVM0; }        \
  BAR;                                                                      \
} while (0)

__global__ void __launch_bounds__(512, 2) gemm_bf16_2phase(
    const short* __restrict__ A, const short* __restrict__ Bw,
    const float* __restrict__ scale_p, const float* __restrict__ bias,
    float* __restrict__ out) {
  __shared__ __align__(16) char lds[131072];

  const int t      = threadIdx.x;        // 0..511
  const int lane   = t & 63;
  const int wave   = t >> 6;
  const int wm     = wave >> 2;          // 0..1  (row half: 128 rows)
  const int wn     = wave & 3;           // 0..3  (col quarter: 64 cols)
  const int lane15 = lane & 15;
  const int lh     = lane >> 4;          // 0..3

  // swizzled read offset within a [st_r][16][64B] region (round-3 verified,
  // zero bank conflicts). XOR, not '+': lh*16 occupies bit 5.
  const int laneoff = (lane15 * 64 + lh * 16) ^ ((lane15 & 8) << 2);

  // stage decode: LDS slot o = l*8192 + t*16 (+ks*16384) holds element at
  // a = o ^ (((o>>9)&1)<<5); here bit9 of o depends only on t.
  const int ax = ((t >> 5) & 1) << 5;
  const int a0 = (t * 16) ^ ax;
  const int a1 = (8192 + t * 16) ^ ax;
  const int r0 = (((a0 >> 10) & 15) << 4) | ((a0 >> 6) & 15);
  const int r1 = (((a1 >> 10) & 15) << 4) | ((a1 >> 6) & 15);
  const int cb = a0 & 63;                // col byte within 64B row (same for l=0,1)

  // XCD-aware swizzle: nwg = 512 (divisible by 8)
  const int bid   = blockIdx.x;
  const int wg    = (bid & 7) * 64 + (bid >> 3);
  const int ntile = wg & 15;             // 16 n-tiles
  const int mtile = wg >> 4;             // 32 m-tiles
  const int m0 = mtile * 256;
  const int n0 = ntile * 256;

  const char* Arow = (const char*)(A + (size_t)m0 * KDIM);
  const char* Brow = (const char*)(Bw + (size_t)n0 * KDIM);

  f32x4 acc[8][4] = {};
  s16x8 af[8], bf[4];

  // Prologue: tile0 q0..q3 (8 loads) + tile1 q0,q1 (4 loads).
  STAGE(Brow, 65536, 0, 0);   // t0 q0
  STAGE(Arow, 0,     0, 0);   // t0 q1
  STAGE(Brow, 65536, 1, 0);   // t0 q2
  STAGE(Arow, 0,     1, 0);   // t0 q3
  STAGE(Brow, 65536, 0, 1);   // t1 q0
  STAGE(Arow, 0,     0, 1);   // t1 q1
  WAITVM4;   // tile0 fully landed; t1 q0,q1 (4 loads) in flight
  BAR;

  // Main: 64 K-tiles; pairs keep buf index compile-time. t = 0..61 full.
#pragma unroll 1
  for (int tp = 0; tp < 31; ++tp) {
    const int t2 = tp * 2;
    KTILE2(t2,     0, 2, 4);
    KTILE2(t2 + 1, 1, 2, 4);
  }
  KTILE2(62, 0, 1, 0);   // stages only t63 q2,q3; drain
  KTILE2(63, 1, 0, -1);

  // Epilogue: D layout col=lane&15, row=(lane>>4)*4+q (m89-verified)
  const float s = scale_p[0];
#pragma unroll
  for (int j = 0; j < 4; ++j) {
    const int col = n0 + wn * 64 + j * 16 + lane15;
    const float bv = bias[col];
#pragma unroll
    for (int i = 0; i < 8; ++i) {
      const int row = m0 + wm * 128 + i * 16 + lh * 4;
#pragma unroll
      for (int q = 0; q < 4; ++q)
        out[(size_t)(row + q) * NDIM + col] = acc[i][j][q] * s + bv;
    }
  }
}

// ---------------- fallback: m97-style reg-staging with on-the-fly conversion ----------------
constexpr int FTILE = 128;
constexpr int FBK   = 64;

__global__ void __launch_bounds__(256) gemm_raw(
    const float* __restrict__ X, const int* __restrict__ W,
    const float* __restrict__ scale_p, const float* __restrict__ bias,
    float* __restrict__ out) {
  __shared__ short As[FTILE * FBK];
  __shared__ short Bs[FTILE * FBK];

  const int t      = threadIdx.x;
  const int lane   = t & 63;
  const int wave   = t >> 6;
  const int wm     = wave >> 1;
  const int wn     = wave & 1;
  const int lane15   = lane & 15;
  const int laneHalf = lane >> 4;

  const int bid   = blockIdx.x;
  const int wg    = (bid & 7) * 256 + (bid >> 3);
  const int ntile = wg & 31;
  const int mtile = wg >> 5;
  const int m0 = mtile * FTILE;
  const int n0 = ntile * FTILE;

  f32x4 acc[4][4] = {};

  for (int k0 = 0; k0 < KDIM; k0 += FBK) {
    __syncthreads();
#pragma unroll
    for (int r = 0; r < 8; ++r) {
      const int f   = r * 256 + t;
      const int row = f >> 4;
      const int c4  = (f & 15) * 4;
      f32x4 v = *(const f32x4*)(X + (size_t)(m0 + row) * KDIM + (k0 + c4));
      s16x4 h;
#pragma unroll
      for (int j = 0; j < 4; ++j) h[j] = f32_to_bf16_rn(v[j]);
      *(s16x4*)&As[row * FBK + c4] = h;

      i32x4 wv = *(const i32x4*)(W + (size_t)(n0 + row) * KDIM + (k0 + c4));
      s16x4 hw;
#pragma unroll
      for (int j = 0; j < 4; ++j) hw[j] = f32_to_bf16_rn((float)wv[j]);
      *(s16x4*)&Bs[row * FBK + c4] = hw;
    }
    __syncthreads();

#pragma unroll
    for (int kk = 0; kk < FBK; kk += 32) {
      const int kb = kk + laneHalf * 8;
      s16x8 af[4], bf[4];
#pragma unroll
      for (int i = 0; i < 4; ++i) {
        af[i] = *(const s16x8*)&As[(wm * 64 + i * 16 + lane15) * FBK + kb];
        bf[i] = *(const s16x8*)&Bs[(wn * 64 + i * 16 + lane15) * FBK + kb];
      }
#pragma unroll
      for (int i = 0; i < 4; ++i)
#pragma unroll
        for (int j = 0; j < 4; ++j)
          acc[i][j] = __builtin_amdgcn_mfma_f32_16x16x32_bf16(af[i], bf[j], acc[i][j], 0, 0, 0);
    }
  }

  const float s = scale_p[0];
#pragma unroll
  for (int j = 0; j < 4; ++j) {
    const int col = n0 + wn * 64 + j * 16 + lane15;
    const float bv = bias[col];
#pragma unroll
    for (int i = 0; i < 4; ++i) {
      const int row = m0 + wm * 64 + i * 16 + laneHalf * 4;
#pragma unroll
      for (int q = 0; q < 4; ++q)
        out[(size_t)(row + q) * NDIM + col] = acc[i][j][q] * s + bv;
    }
  }
}

extern "C" void kernel_launch(void* const* d_in, const int* in_sizes, int n_in,
                              void* d_out, int out_size, void* d_ws, size_t ws_size,
                              hipStream_t stream) {
  const float* x     = (const float*)d_in[0];
  const int*   w     = (const int*)d_in[1];    // integer inputs materialize as int32
  const float* scale = (const float*)d_in[2];
  const float* bias  = (const float*)d_in[3];
  float* out = (float*)d_out;

  const size_t a_elems = (size_t)MDIM * KDIM;  // 33,554,432
  const size_t b_elems = (size_t)NDIM * KDIM;  // 16,777,216
  const size_t need    = (a_elems + b_elems) * sizeof(short);  // 100,663,296 B

  if (ws_size >= need) {
    short* Abf = (short*)d_ws;
    short* Wbf = Abf + a_elems;
    cvt_x_kernel<<<2048, 256, 0, stream>>>(x, Abf, (int)(a_elems / 8));
    cvt_w_kernel<<<2048, 256, 0, stream>>>(w, Wbf, (int)(b_elems / 8));
    const int nwg = (MDIM / 256) * (NDIM / 256);  // 32*16 = 512
    gemm_bf16_2phase<<<nwg, 512, 0, stream>>>(Abf, Wbf, scale, bias, out);
  } else {
    const int nwg = (MDIM / FTILE) * (NDIM / FTILE);  // 2048
    gemm_raw<<<nwg, 256, 0, stream>>>(x, w, scale, bias, out);
  }
}

// Round 6
// 285.452 us; speedup vs baseline: 1.0890x; 1.0500x over previous
//
#include <hip/hip_runtime.h>
#include <stdint.h>
#include <stddef.h>

// Problem geometry (B=4, S=2048, DIN=4096, DOUT=4096)
constexpr int MDIM = 8192;   // B*S
constexpr int NDIM = 4096;   // DOUT
constexpr int KDIM = 4096;   // DIN

using f32x4 = __attribute__((ext_vector_type(4))) float;
using s16x4 = __attribute__((ext_vector_type(4))) short;
using s16x8 = __attribute__((ext_vector_type(8))) short;
using i32x4 = __attribute__((ext_vector_type(4))) int;

__device__ __forceinline__ short f32_to_bf16_rn(float f) {
  union { float f; uint32_t u; } v; v.f = f;
  uint32_t r = (v.u + 0x7FFFu + ((v.u >> 16) & 1u)) >> 16;  // RTN-even
  return (short)(uint16_t)r;
}

// ---------------- prepass: f32 -> bf16 ----------------
__global__ void __launch_bounds__(256) cvt_x_kernel(const float* __restrict__ in,
                                                    short* __restrict__ out, int n8) {
  int i = blockIdx.x * 256 + threadIdx.x;
  const int stride = gridDim.x * 256;
  for (; i < n8; i += stride) {
    const f32x4* p = (const f32x4*)(in + (size_t)i * 8);
    f32x4 a = p[0];
    f32x4 b = p[1];
    s16x8 o;
#pragma unroll
    for (int j = 0; j < 4; ++j) { o[j] = f32_to_bf16_rn(a[j]); o[j + 4] = f32_to_bf16_rn(b[j]); }
    *(s16x8*)(out + (size_t)i * 8) = o;
  }
}

// ---------------- prepass: int32 (quantized weight) -> bf16 (exact) ----------------
__global__ void __launch_bounds__(256) cvt_w_kernel(const int* __restrict__ in,
                                                    short* __restrict__ out, int n8) {
  int i = blockIdx.x * 256 + threadIdx.x;
  const int stride = gridDim.x * 256;
  for (; i < n8; i += stride) {
    const i32x4* p = (const i32x4*)(in + (size_t)i * 8);
    i32x4 a = p[0];
    i32x4 b = p[1];
    s16x8 o;
#pragma unroll
    for (int j = 0; j < 4; ++j) {
      o[j]     = f32_to_bf16_rn((float)a[j]);
      o[j + 4] = f32_to_bf16_rn((float)b[j]);
    }
    *(s16x8*)(out + (size_t)i * 8) = o;
  }
}

// =====================================================================
// 256x256 GEMM, 4-region pipelined variant (register-fragment double
// buffering): reads for region p+1 overlap MFMA of region p in the SAME
// barrier window; ONE barrier per region (4/K-tile).
//   A [M][K] bf16, Bw [N][K] bf16 (= B^T), C = A*Bw^T * scale + bias
// LDS per matrix per buffer (32 KiB): subtiled [ks][st_r][16][64B],
// XOR swizzle phys = lin ^ (((lin>>9)&1)<<5)  (st_16x32).
// Staged via global_load_lds (linear dest) from inverse-swizzled source.
//
// Schedule per tile t (cur=t&1, nxt=(t+1)&1), frag sets E=0, O=1:
//  R1: rd afO:=A4-7(cur,ks0);            stage B-ks1(t+1); MFMA acc[0-3](afE,bfE); vmcnt(6); BAR
//  R2: rd afE:=A0-3(cur,ks1), bfO:=B(cur,ks1); stage A-ks1(t+1); MFMA acc[4-7](afO,bfE);          BAR
//  R3: rd afO:=A4-7(cur,ks1);            stage B-ks0(t+2); MFMA acc[0-3](afE,bfO); vmcnt(6); BAR
//  R4: rd afE:=A0-3(nxt,ks0), bfE:=B(nxt,ks0); stage A-ks0(t+2); MFMA acc[4-7](afO,bfO);          BAR
// RAW: vmcnt(6)@end-R1 -> q2,q3(t) landed before R2 reads (issued 3 regions
//      earlier); vmcnt(6)@end-R3 -> q0,q1(t+1) landed before R4 reads.
// WAR: every staged region's old data had its consuming lgkm-wait >=1
//      barrier before the stage (derived per-slot; see session notes).
// Steady-state in-flight: 6-10 loads; oldest waited-on is 3 regions old
// (~1500 cyc > 900-cyc HBM latency) -> no vmcnt stall (round-5's bug fixed).
// =====================================================================

#define BAR asm volatile("s_barrier" ::: "memory")
#define WAITVM(n) asm volatile("s_waitcnt vmcnt(" #n ")" ::: "memory")

#define GLL(src, dst) __builtin_amdgcn_global_load_lds(                     \
    (const __attribute__((address_space(1))) void*)(src),                   \
    (__attribute__((address_space(3))) void*)(dst), 16, 0, 0)

// grow: const char* global row base; ldsmat: 0 (A) or 65536 (B)
#define STAGE(grow, ldsmat, ks, tau) do {                                   \
  const int buf_ = (tau) & 1;                                               \
  GLL((grow) + (size_t)r0 * 8192 + (size_t)(tau) * 128 + (ks) * 64 + cb,    \
      lds + (ldsmat) + buf_ * 32768 + (ks) * 16384 + t * 16);               \
  GLL((grow) + (size_t)r1 * 8192 + (size_t)(tau) * 128 + (ks) * 64 + cb,    \
      lds + (ldsmat) + buf_ * 32768 + (ks) * 16384 + 8192 + t * 16);        \
} while (0)

#define LDA(bufc, ks, i) (*(const s16x8*)(lds + (bufc) * 32768 + (ks) * 16384 \
    + (wm * 8 + (i)) * 1024 + laneoff))
#define LDB(bufc, ks, j) (*(const s16x8*)(lds + 65536 + (bufc) * 32768        \
    + (ks) * 16384 + (wn * 4 + (j)) * 1024 + laneoff))

#define READ_A4(set, bufc, ks, base) do {                                   \
  _Pragma("unroll") for (int i_ = 0; i_ < 4; ++i_)                          \
    af[set][i_] = LDA(bufc, ks, (base) + i_);                               \
} while (0)
#define READ_B4(set, bufc, ks) do {                                         \
  _Pragma("unroll") for (int j_ = 0; j_ < 4; ++j_)                          \
    bf[set][j_] = LDB(bufc, ks, j_);                                        \
} while (0)

#define MFMA16(accbase, aset, bset) do {                                    \
  __builtin_amdgcn_s_setprio(1);                                            \
  _Pragma("unroll") for (int i_ = 0; i_ < 4; ++i_)                          \
  _Pragma("unroll") for (int j_ = 0; j_ < 4; ++j_)                          \
    acc[(accbase) + i_][j_] = __builtin_amdgcn_mfma_f32_16x16x32_bf16(      \
        af[aset][i_], bf[bset][j_], acc[(accbase) + i_][j_], 0, 0, 0);      \
  __builtin_amdgcn_s_setprio(0);                                            \
} while (0)

// One K-tile = 4 single-barrier regions.
// sN: stage on/off per region; vm1/vm3: vmcnt arg (-1 = none); r4: do R4 reads.
#define KTILE(t_, cur, nxt, s1, s2, s3, s4, vm1, vm3, r4) do {              \
  /* R1 */                                                                  \
  READ_A4(1, cur, 0, 4);                                                    \
  if (s1) STAGE(Brow, 65536, 1, (t_) + 1);                                  \
  MFMA16(0, 0, 0);                                                          \
  if ((vm1) == 6) { WAITVM(6); } else if ((vm1) == 0) { WAITVM(0); }        \
  BAR;                                                                      \
  /* R2 */                                                                  \
  READ_A4(0, cur, 1, 0); READ_B4(1, cur, 1);                                \
  if (s2) STAGE(Arow, 0, 1, (t_) + 1);                                      \
  MFMA16(4, 1, 0);                                                          \
  BAR;                                                                      \
  /* R3 */                                                                  \
  READ_A4(1, cur, 1, 4);                                                    \
  if (s3) STAGE(Brow, 65536, 0, (t_) + 2);                                  \
  MFMA16(0, 0, 1);                                                          \
  if ((vm3) == 6) { WAITVM(6); } else if ((vm3) == 4) { WAITVM(4); }        \
  BAR;                                                                      \
  /* R4 */                                                                  \
  if (r4) { READ_A4(0, nxt, 0, 0); READ_B4(0, nxt, 0); }                    \
  if (s4) STAGE(Arow, 0, 0, (t_) + 2);                                      \
  MFMA16(4, 1, 1);                                                          \
  BAR;                                                                      \
} while (0)

__global__ void __launch_bounds__(512, 2) gemm_bf16_pipe(
    const short* __restrict__ A, const short* __restrict__ Bw,
    const float* __restrict__ scale_p, const float* __restrict__ bias,
    float* __restrict__ out) {
  __shared__ __align__(16) char lds[131072];

  const int t      = threadIdx.x;        // 0..511
  const int lane   = t & 63;
  const int wave   = t >> 6;
  const int wm     = wave >> 2;          // 0..1  (row half: 128 rows)
  const int wn     = wave & 3;           // 0..3  (col quarter: 64 cols)
  const int lane15 = lane & 15;
  const int lh     = lane >> 4;          // 0..3

  // swizzled read offset (round-3 verified, zero bank conflicts).
  // XOR, not '+': lh*16 occupies bit 5.
  const int laneoff = (lane15 * 64 + lh * 16) ^ ((lane15 & 8) << 2);

  // stage decode: LDS slot o = l*8192 + t*16 holds element a = o ^ (((o>>9)&1)<<5)
  const int ax = ((t >> 5) & 1) << 5;
  const int a0 = (t * 16) ^ ax;
  const int a1 = (8192 + t * 16) ^ ax;
  const int r0 = (((a0 >> 10) & 15) << 4) | ((a0 >> 6) & 15);
  const int r1 = (((a1 >> 10) & 15) << 4) | ((a1 >> 6) & 15);
  const int cb = a0 & 63;

  // XCD-aware swizzle: nwg = 512 (divisible by 8)
  const int bid   = blockIdx.x;
  const int wg    = (bid & 7) * 64 + (bid >> 3);
  const int ntile = wg & 15;             // 16 n-tiles
  const int mtile = wg >> 4;             // 32 m-tiles
  const int m0 = mtile * 256;
  const int n0 = ntile * 256;

  const char* Arow = (const char*)(A + (size_t)m0 * KDIM);
  const char* Brow = (const char*)(Bw + (size_t)n0 * KDIM);

  f32x4 acc[8][4] = {};
  s16x8 af[2][4], bf[2][4];

  // Prologue: q0-q3(t0), q0,q1(t1) = 6 stages (12 loads/thread-pair slice).
  STAGE(Brow, 65536, 0, 0);   // t0 q0: B ks0
  STAGE(Arow, 0,     0, 0);   // t0 q1: A ks0
  STAGE(Brow, 65536, 1, 0);   // t0 q2: B ks1
  STAGE(Arow, 0,     1, 0);   // t0 q3: A ks1
  STAGE(Brow, 65536, 0, 1);   // t1 q0
  STAGE(Arow, 0,     0, 1);   // t1 q1
  WAITVM(8);                  // q0,q1(t0) landed; 4 stages in flight
  BAR;
  // pre-read frags for R1(t0): afE = A0-3(t0,ks0), bfE = B(t0,ks0)
  READ_A4(0, 0, 0, 0);
  READ_B4(0, 0, 0);

  // Main: tiles 0..61 in pairs (buf index compile-time), then 62, 63.
#pragma unroll 1
  for (int tp = 0; tp < 31; ++tp) {
    const int t2 = tp * 2;
    KTILE(t2,     0, 1, 1, 1, 1, 1, 6, 6, 1);
    KTILE(t2 + 1, 1, 0, 1, 1, 1, 1, 6, 6, 1);
  }
  KTILE(62, 0, 1, 1, 1, 0, 0, 6, 4, 1);   // stages q2,q3(63) only
  KTILE(63, 1, 0, 0, 0, 0, 0, 0, -1, 0);  // drain; no reads for t=64

  // Epilogue: D layout col=lane&15, row=(lane>>4)*4+q (m89-verified)
  const float s = scale_p[0];
#pragma unroll
  for (int j = 0; j < 4; ++j) {
    const int col = n0 + wn * 64 + j * 16 + lane15;
    const float bv = bias[col];
#pragma unroll
    for (int i = 0; i < 8; ++i) {
      const int row = m0 + wm * 128 + i * 16 + lh * 4;
#pragma unroll
      for (int q = 0; q < 4; ++q)
        out[(size_t)(row + q) * NDIM + col] = acc[i][j][q] * s + bv;
    }
  }
}

// ---------------- fallback: m97-style reg-staging with on-the-fly conversion ----------------
constexpr int FTILE = 128;
constexpr int FBK   = 64;

__global__ void __launch_bounds__(256) gemm_raw(
    const float* __restrict__ X, const int* __restrict__ W,
    const float* __restrict__ scale_p, const float* __restrict__ bias,
    float* __restrict__ out) {
  __shared__ short As[FTILE * FBK];
  __shared__ short Bs[FTILE * FBK];

  const int t      = threadIdx.x;
  const int lane   = t & 63;
  const int wave   = t >> 6;
  const int wm     = wave >> 1;
  const int wn     = wave & 1;
  const int lane15   = lane & 15;
  const int laneHalf = lane >> 4;

  const int bid   = blockIdx.x;
  const int wg    = (bid & 7) * 256 + (bid >> 3);
  const int ntile = wg & 31;
  const int mtile = wg >> 5;
  const int m0 = mtile * FTILE;
  const int n0 = ntile * FTILE;

  f32x4 acc[4][4] = {};

  for (int k0 = 0; k0 < KDIM; k0 += FBK) {
    __syncthreads();
#pragma unroll
    for (int r = 0; r < 8; ++r) {
      const int f   = r * 256 + t;
      const int row = f >> 4;
      const int c4  = (f & 15) * 4;
      f32x4 v = *(const f32x4*)(X + (size_t)(m0 + row) * KDIM + (k0 + c4));
      s16x4 h;
#pragma unroll
      for (int j = 0; j < 4; ++j) h[j] = f32_to_bf16_rn(v[j]);
      *(s16x4*)&As[row * FBK + c4] = h;

      i32x4 wv = *(const i32x4*)(W + (size_t)(n0 + row) * KDIM + (k0 + c4));
      s16x4 hw;
#pragma unroll
      for (int j = 0; j < 4; ++j) hw[j] = f32_to_bf16_rn((float)wv[j]);
      *(s16x4*)&Bs[row * FBK + c4] = hw;
    }
    __syncthreads();

#pragma unroll
    for (int kk = 0; kk < FBK; kk += 32) {
      const int kb = kk + laneHalf * 8;
      s16x8 af[4], bf[4];
#pragma unroll
      for (int i = 0; i < 4; ++i) {
        af[i] = *(const s16x8*)&As[(wm * 64 + i * 16 + lane15) * FBK + kb];
        bf[i] = *(const s16x8*)&Bs[(wn * 64 + i * 16 + lane15) * FBK + kb];
      }
#pragma unroll
      for (int i = 0; i < 4; ++i)
#pragma unroll
        for (int j = 0; j < 4; ++j)
          acc[i][j] = __builtin_amdgcn_mfma_f32_16x16x32_bf16(af[i], bf[j], acc[i][j], 0, 0, 0);
    }
  }

  const float s = scale_p[0];
#pragma unroll
  for (int j = 0; j < 4; ++j) {
    const int col = n0 + wn * 64 + j * 16 + lane15;
    const float bv = bias[col];
#pragma unroll
    for (int i = 0; i < 4; ++i) {
      const int row = m0 + wm * 64 + i * 16 + laneHalf * 4;
#pragma unroll
      for (int q = 0; q < 4; ++q)
        out[(size_t)(row + q) * NDIM + col] = acc[i][j][q] * s + bv;
    }
  }
}

extern "C" void kernel_launch(void* const* d_in, const int* in_sizes, int n_in,
                              void* d_out, int out_size, void* d_ws, size_t ws_size,
                              hipStream_t stream) {
  const float* x     = (const float*)d_in[0];
  const int*   w     = (const int*)d_in[1];    // integer inputs materialize as int32
  const float* scale = (const float*)d_in[2];
  const float* bias  = (const float*)d_in[3];
  float* out = (float*)d_out;

  const size_t a_elems = (size_t)MDIM * KDIM;  // 33,554,432
  const size_t b_elems = (size_t)NDIM * KDIM;  // 16,777,216
  const size_t need    = (a_elems + b_elems) * sizeof(short);  // 100,663,296 B

  if (ws_size >= need) {
    short* Abf = (short*)d_ws;
    short* Wbf = Abf + a_elems;
    cvt_x_kernel<<<2048, 256, 0, stream>>>(x, Abf, (int)(a_elems / 8));
    cvt_w_kernel<<<2048, 256, 0, stream>>>(w, Wbf, (int)(b_elems / 8));
    const int nwg = (MDIM / 256) * (NDIM / 256);  // 32*16 = 512
    gemm_bf16_pipe<<<nwg, 512, 0, stream>>>(Abf, Wbf, scale, bias, out);
  } else {
    const int nwg = (MDIM / FTILE) * (NDIM / FTILE);  // 2048
    gemm_raw<<<nwg, 256, 0, stream>>>(x, w, scale, bias, out);
  }
}